// Round 9
// baseline (135.677 us; speedup 1.0000x reference)
//
#include <hip/hip_runtime.h>
#include <hip/hip_bf16.h>

#define N_ROWS 16384
#define DIM 128

constexpr float INV_T = 1.0f / 0.07f;                 // 14.2857...
constexpr float LOG2E = 1.4426950408889634f;
constexpr float C1    = INV_T * LOG2E;                // exp2 scale, folded into A
constexpr float LN2   = 0.69314718055994530942f;

typedef short bf16x8 __attribute__((ext_vector_type(8)));
typedef float f32x16 __attribute__((ext_vector_type(16)));

__device__ __forceinline__ ushort f2bf(float x) {
    unsigned u = __float_as_uint(x);
    u += 0x7fffu + ((u >> 16) & 1u);                  // RTNE
    return (ushort)(u >> 16);
}

// p stored PRE-TILED in B-fragment order: one 64-col tile = 16KB contiguous.
//   layout [tile64][ct2][kf8][hi2][c31 32]x(8 bf16)
//   col j: tile=j>>6, ct=(j>>5)&1, c31=j&31 ; k: kf=k>>4, hi=(k>>3)&1
#define TILE_U16 8192                 /* 64 cols x 128 k = 16 KB          */
#define TILE_BYTES 16384
#define BM 256                        /* rows per block (4 waves x 64)    */
#define WROWS 64
#define COLSPLIT 32                   /* grid 2048 -> 8 blocks/CU supply  */
#define COLS_PER (N_ROWS / COLSPLIT)  /* 512 */
#define NJT (COLS_PER / 64)           /* 8   */

// ---------------------------------------------------------------------------
// Kernel 1: normalize; A scaled by C1 (exp2 fold); P written tiled;
// exact fp32 diagonal logit.  (unchanged from R3/R6 — proven)
// ---------------------------------------------------------------------------
__global__ __launch_bounds__(256) void norm_kernel(
    const float* __restrict__ A, const float* __restrict__ P,
    ushort* __restrict__ a16, ushort* __restrict__ p16t,
    float* __restrict__ diag)
{
    int row  = blockIdx.x * 4 + (threadIdx.x >> 6);
    int lane = threadIdx.x & 63;
    float2 av = *(const float2*)(A + (size_t)row * DIM + lane * 2);
    float2 pv = *(const float2*)(P + (size_t)row * DIM + lane * 2);
    float ssa = av.x * av.x + av.y * av.y;
    float ssp = pv.x * pv.x + pv.y * pv.y;
    float dp  = av.x * pv.x + av.y * pv.y;
    #pragma unroll
    for (int m = 1; m < 64; m <<= 1) {
        ssa += __shfl_xor(ssa, m);
        ssp += __shfl_xor(ssp, m);
        dp  += __shfl_xor(dp,  m);
    }
    float ra = 1.0f / fmaxf(sqrtf(ssa), 1e-12f);
    float rp = 1.0f / fmaxf(sqrtf(ssp), 1e-12f);
    if (lane == 0) diag[row] = dp * ra * rp * INV_T;
    float sa = ra * C1;
    ushort2 a2, p2;
    a2.x = f2bf(av.x * sa); a2.y = f2bf(av.y * sa);
    p2.x = f2bf(pv.x * rp); p2.y = f2bf(pv.y * rp);
    *(ushort2*)(a16 + (size_t)row * DIM + lane * 2) = a2;
    // tiled p: k = lane*2 -> kf=lane>>3, hi=(lane>>2)&1, within = (lane&3)*2
    size_t off = (size_t)(row >> 6) * TILE_U16 + ((row >> 5) & 1) * 4096
               + (lane >> 3) * 512 + ((lane >> 2) & 1) * 256
               + (row & 31) * 8 + (lane & 3) * 2;
    *(ushort2*)(p16t + off) = p2;
}

// ---------------------------------------------------------------------------
// Kernel 2: per-row sum of exp2(C1*cos - C1) via 32x32x16 bf16 MFMA.
// Wave owns 64 rows (A frags in regs). B read straight from L2 (4MB total,
// XCD-pinned segments). NO LDS, NO barriers: latency hidden by occupancy.
// Grid 2048 = 8 blocks/CU supply; VGPR~100 -> ~5 waves/SIMD resident.
// REG-CAP DISCIPLINE: (256,2) ONLY. Any tighter cap makes the unified
// VGPR/AGPR split starve arch VGPRs and spill to scratch:
//   (256,3) -> VGPR=84, 280MB scratch (R2/R4); (256,4) -> VGPR=64, 935MB (R6).
// This kernel is byte-identical to R6 (passed, absmax 0.0) except the bound.
// ---------------------------------------------------------------------------
__global__ __launch_bounds__(256, 2) void lse_kernel(
    const ushort* __restrict__ a16, const ushort* __restrict__ p16t,
    float* __restrict__ s_accum)
{
    int colseg = blockIdx.x & (COLSPLIT - 1);   // bid%8 = XCD -> seg pinned
    int rowblk = blockIdx.x / COLSPLIT;
    int wave = threadIdx.x >> 6;
    int lane = threadIdx.x & 63;
    int c31  = lane & 31, hi = lane >> 5;
    int row0 = rowblk * BM + wave * WROWS;

    // A fragments: 2 row-tiles x 8 K-frags (K=16 each), 8 bf16/lane.
    bf16x8 afrag[2][8];
    #pragma unroll
    for (int t = 0; t < 2; ++t)
        #pragma unroll
        for (int kf = 0; kf < 8; ++kf)
            afrag[t][kf] = *(const bf16x8*)(
                a16 + (size_t)(row0 + t * 32 + c31) * DIM + kf * 16 + hi * 8);

    float s0[16], s1[16];
    #pragma unroll
    for (int r = 0; r < 16; ++r) { s0[r] = 0.f; s1[r] = 0.f; }

    // per-lane base into the tiled B segment: lane*8 u16 = lane*16 B
    const ushort* seg = p16t + (size_t)colseg * NJT * TILE_U16 + lane * 8;

    for (int jt = 0; jt < NJT; ++jt) {
        // two bases so every kf load folds into the 13-bit imm offset
        const ushort* tb0 = seg + (size_t)jt * TILE_U16;
        const ushort* tb1 = tb0 + 4096;
        #pragma unroll
        for (int ct = 0; ct < 2; ++ct) {
            const ushort* tb = ct ? tb1 : tb0;
            f32x16 acc0, acc1;
            #pragma unroll
            for (int r = 0; r < 16; ++r) { acc0[r] = -C1; acc1[r] = -C1; }
            #pragma unroll
            for (int kf = 0; kf < 8; ++kf) {
                bf16x8 b = *(const bf16x8*)(tb + kf * 512);
                acc0 = __builtin_amdgcn_mfma_f32_32x32x16_bf16(
                    afrag[0][kf], b, acc0, 0, 0, 0);
                acc1 = __builtin_amdgcn_mfma_f32_32x32x16_bf16(
                    afrag[1][kf], b, acc1, 0, 0, 0);
            }
            #pragma unroll
            for (int r = 0; r < 16; ++r) {
                s0[r] += __builtin_amdgcn_exp2f(acc0[r]);
                s1[r] += __builtin_amdgcn_exp2f(acc1[r]);
            }
        }
    }

    // reduce each row's 32 column-lanes (within each 32-lane half), one atomic
    #pragma unroll
    for (int t = 0; t < 2; ++t)
        #pragma unroll
        for (int r = 0; r < 16; ++r) {
            float v = (t ? s1[r] : s0[r]);
            v += __shfl_xor(v, 1);
            v += __shfl_xor(v, 2);
            v += __shfl_xor(v, 4);
            v += __shfl_xor(v, 8);
            v += __shfl_xor(v, 16);
            if (c31 == 0)
                atomicAdd(&s_accum[row0 + t * 32 + (r & 3) + 8 * (r >> 2) + 4 * hi], v);
        }
}

// ---------------------------------------------------------------------------
// Kernel 3: loss = mean( ln(s_i) + 1/T - diag_i )
// ---------------------------------------------------------------------------
__global__ __launch_bounds__(1024) void finalize_kernel(
    const float* __restrict__ s_acc, const float* __restrict__ diag,
    float* __restrict__ out)
{
    float acc = 0.f;
    int t = threadIdx.x;
    #pragma unroll
    for (int i = 0; i < 4; ++i) {
        int idx = (i * 1024 + t) * 4;
        float4 sv = *(const float4*)(s_acc + idx);
        float4 dv = *(const float4*)(diag + idx);
        acc += __builtin_amdgcn_logf(sv.x) * LN2 + INV_T - dv.x;
        acc += __builtin_amdgcn_logf(sv.y) * LN2 + INV_T - dv.y;
        acc += __builtin_amdgcn_logf(sv.z) * LN2 + INV_T - dv.z;
        acc += __builtin_amdgcn_logf(sv.w) * LN2 + INV_T - dv.w;
    }
    #pragma unroll
    for (int m = 1; m < 64; m <<= 1) acc += __shfl_xor(acc, m);
    __shared__ float wsum[16];
    if ((t & 63) == 0) wsum[t >> 6] = acc;
    __syncthreads();
    if (t == 0) {
        float r = 0.f;
        #pragma unroll
        for (int i = 0; i < 16; ++i) r += wsum[i];
        out[0] = r / (float)N_ROWS;
    }
}

// ---------------------------------------------------------------------------
extern "C" void kernel_launch(void* const* d_in, const int* in_sizes, int n_in,
                              void* d_out, int out_size, void* d_ws, size_t ws_size,
                              hipStream_t stream)
{
    const float* A = (const float*)d_in[0];
    const float* P = (const float*)d_in[1];
    float* out = (float*)d_out;

    char* ws = (char*)d_ws;
    ushort* a16  = (ushort*)ws;                                   // 4 MB
    ushort* p16t = (ushort*)(ws + (size_t)4 * 1024 * 1024);       // 4 MB tiled
    float*  diag = (float*)(ws + (size_t)8 * 1024 * 1024);        // 64 KB
    float*  sacc = (float*)(ws + (size_t)8 * 1024 * 1024 + 65536);

    hipMemsetAsync(sacc, 0, N_ROWS * sizeof(float), stream);
    norm_kernel<<<N_ROWS / 4, 256, 0, stream>>>(A, P, a16, p16t, diag);
    lse_kernel<<<(N_ROWS / BM) * COLSPLIT, 256, 0, stream>>>(a16, p16t, sacc);
    finalize_kernel<<<1, 1024, 0, stream>>>(sacc, diag, out);
}

// Round 10
// 100.590 us; speedup vs baseline: 1.3488x; 1.3488x over previous
//
#include <hip/hip_runtime.h>
#include <hip/hip_bf16.h>

#define N_ROWS 16384
#define DIM 128

constexpr float INV_T = 1.0f / 0.07f;                 // 14.2857...
constexpr float LOG2E = 1.4426950408889634f;
constexpr float C1    = INV_T * LOG2E;                // exp2 scale, folded into A
constexpr float LN2   = 0.69314718055994530942f;

typedef short bf16x8 __attribute__((ext_vector_type(8)));
typedef float f32x16 __attribute__((ext_vector_type(16)));

typedef const __attribute__((address_space(1))) void* gptr1_t;
typedef __attribute__((address_space(3))) void*       sptr3_t;

__device__ __forceinline__ ushort f2bf(float x) {
    unsigned u = __float_as_uint(x);
    u += 0x7fffu + ((u >> 16) & 1u);                  // RTNE
    return (ushort)(u >> 16);
}

// p stored PRE-TILED in B-fragment order: one 64-col tile = 16KB contiguous.
//   layout [tile64][ct2][kf8][hi2][c31 32]x(8 bf16)
//   col j: tile=j>>6, ct=(j>>5)&1, c31=j&31 ; k: kf=k>>4, hi=(k>>3)&1
#define TILE_U16 8192                 /* 64 cols x 128 k = 16 KB          */
#define TILE_BYTES 16384
#define BM 256                        /* rows per block (4 waves x 64)    */
#define WROWS 64
#define COLSPLIT 16
#define COLS_PER (N_ROWS / COLSPLIT)  /* 1024 */
#define NJT (COLS_PER / 64)           /* 16   */

// ---------------------------------------------------------------------------
// Kernel 1: normalize; A scaled by C1 (exp2 fold); P written tiled;
// exact fp32 diagonal logit.  (proven since R3)
// ---------------------------------------------------------------------------
__global__ __launch_bounds__(256) void norm_kernel(
    const float* __restrict__ A, const float* __restrict__ P,
    ushort* __restrict__ a16, ushort* __restrict__ p16t,
    float* __restrict__ diag)
{
    int row  = blockIdx.x * 4 + (threadIdx.x >> 6);
    int lane = threadIdx.x & 63;
    float2 av = *(const float2*)(A + (size_t)row * DIM + lane * 2);
    float2 pv = *(const float2*)(P + (size_t)row * DIM + lane * 2);
    float ssa = av.x * av.x + av.y * av.y;
    float ssp = pv.x * pv.x + pv.y * pv.y;
    float dp  = av.x * pv.x + av.y * pv.y;
    #pragma unroll
    for (int m = 1; m < 64; m <<= 1) {
        ssa += __shfl_xor(ssa, m);
        ssp += __shfl_xor(ssp, m);
        dp  += __shfl_xor(dp,  m);
    }
    float ra = 1.0f / fmaxf(sqrtf(ssa), 1e-12f);
    float rp = 1.0f / fmaxf(sqrtf(ssp), 1e-12f);
    if (lane == 0) diag[row] = dp * ra * rp * INV_T;
    float sa = ra * C1;
    ushort2 a2, p2;
    a2.x = f2bf(av.x * sa); a2.y = f2bf(av.y * sa);
    p2.x = f2bf(pv.x * rp); p2.y = f2bf(pv.y * rp);
    *(ushort2*)(a16 + (size_t)row * DIM + lane * 2) = a2;
    // tiled p: k = lane*2 -> kf=lane>>3, hi=(lane>>2)&1, within = (lane&3)*2
    size_t off = (size_t)(row >> 6) * TILE_U16 + ((row >> 5) & 1) * 4096
               + (lane >> 3) * 512 + ((lane >> 2) & 1) * 256
               + (row & 31) * 8 + (lane & 3) * 2;
    *(ushort2*)(p16t + off) = p2;
}

// ---------------------------------------------------------------------------
// Kernel 2: per-row sum of exp2(C1*cos - C1) via 32x32x16 bf16 MFMA.
// R5 baseline (87us) + two edits:
//  (1) cinit as MFMA srcC on peeled kf=0: kills 32 v_mov inits per ct and
//      the init->MFMA dependency  [probe: if NaN, this is R8's defect]
//  (2) s_setprio(1) around the MFMA cluster (T5; blocks are barrier-
//      independent so SIMD-mates sit at different phases)
// REG-CAP DISCIPLINE: (256,2) ONLY — tighter caps spill (R2/R4/R6).
// ---------------------------------------------------------------------------
__global__ __launch_bounds__(256, 2) void lse_kernel(
    const ushort* __restrict__ a16, const ushort* __restrict__ p16t,
    float* __restrict__ s_accum)
{
    __shared__ __attribute__((aligned(16))) ushort btile[2][TILE_U16];

    int colseg = blockIdx.x & (COLSPLIT - 1);   // round-robin -> XCD-pinned
    int rowblk = blockIdx.x / COLSPLIT;
    int wave = threadIdx.x >> 6;
    int lane = threadIdx.x & 63;
    int c31  = lane & 31, hi = lane >> 5;
    int row0 = rowblk * BM + wave * WROWS;

    // A fragments: 2 row-tiles x 8 K-frags (K=16 each), 8 bf16/lane.
    bf16x8 afrag[2][8];
    #pragma unroll
    for (int t = 0; t < 2; ++t)
        #pragma unroll
        for (int kf = 0; kf < 8; ++kf)
            afrag[t][kf] = *(const bf16x8*)(
                a16 + (size_t)(row0 + t * 32 + c31) * DIM + kf * 16 + hi * 8);

    f32x16 cinit;
    #pragma unroll
    for (int r = 0; r < 16; ++r) cinit[r] = -C1;

    float s0[16], s1[16];
    #pragma unroll
    for (int r = 0; r < 16; ++r) { s0[r] = 0.f; s1[r] = 0.f; }

    const char* seg = (const char*)p16t + (size_t)colseg * NJT * TILE_BYTES;

    // prologue: stage tile 0 into buffer 0 (4 x 1KB chunks per wave)
    #pragma unroll
    for (int i = 0; i < 16; ++i)
        if ((i & 3) == wave)
            __builtin_amdgcn_global_load_lds(
                (gptr1_t)(seg + i * 1024 + lane * 16),
                (sptr3_t)((char*)&btile[0][0] + i * 1024), 16, 0, 0);

    int cur = 0;
    for (int jt = 0; jt < NJT; ++jt) {
        __syncthreads();   // tile[cur] ready; prev tile's reads done

        if (jt + 1 < NJT) {
            const char* src = seg + (size_t)(jt + 1) * TILE_BYTES;
            char* dst = (char*)&btile[cur ^ 1][0];
            #pragma unroll
            for (int i = 0; i < 16; ++i)
                if ((i & 3) == wave)
                    __builtin_amdgcn_global_load_lds(
                        (gptr1_t)(src + i * 1024 + lane * 16),
                        (sptr3_t)(dst + i * 1024), 16, 0, 0);
        }

        const ushort* tb = &btile[cur][0] + lane * 8;
        #pragma unroll
        for (int ct = 0; ct < 2; ++ct) {
            // peel kf=0: srcC = cinit (no acc init movs)
            bf16x8 b0 = *(const bf16x8*)(tb + ct * 4096);
            __builtin_amdgcn_s_setprio(1);
            f32x16 acc0 = __builtin_amdgcn_mfma_f32_32x32x16_bf16(
                afrag[0][0], b0, cinit, 0, 0, 0);
            f32x16 acc1 = __builtin_amdgcn_mfma_f32_32x32x16_bf16(
                afrag[1][0], b0, cinit, 0, 0, 0);
            #pragma unroll
            for (int kf = 1; kf < 8; ++kf) {
                bf16x8 b = *(const bf16x8*)(tb + ct * 4096 + kf * 512);
                acc0 = __builtin_amdgcn_mfma_f32_32x32x16_bf16(
                    afrag[0][kf], b, acc0, 0, 0, 0);
                acc1 = __builtin_amdgcn_mfma_f32_32x32x16_bf16(
                    afrag[1][kf], b, acc1, 0, 0, 0);
            }
            __builtin_amdgcn_s_setprio(0);
            #pragma unroll
            for (int r = 0; r < 16; ++r) {
                s0[r] += __builtin_amdgcn_exp2f(acc0[r]);
                s1[r] += __builtin_amdgcn_exp2f(acc1[r]);
            }
        }
        cur ^= 1;
    }

    // reduce each row's 32 column-lanes (within each 32-lane half), one atomic
    #pragma unroll
    for (int t = 0; t < 2; ++t)
        #pragma unroll
        for (int r = 0; r < 16; ++r) {
            float v = (t ? s1[r] : s0[r]);
            v += __shfl_xor(v, 1);
            v += __shfl_xor(v, 2);
            v += __shfl_xor(v, 4);
            v += __shfl_xor(v, 8);
            v += __shfl_xor(v, 16);
            if (c31 == 0)
                atomicAdd(&s_accum[row0 + t * 32 + (r & 3) + 8 * (r >> 2) + 4 * hi], v);
        }
}

// ---------------------------------------------------------------------------
// Kernel 3: loss = mean( ln(s_i) + 1/T - diag_i )
// ---------------------------------------------------------------------------
__global__ __launch_bounds__(1024) void finalize_kernel(
    const float* __restrict__ s_acc, const float* __restrict__ diag,
    float* __restrict__ out)
{
    float acc = 0.f;
    int t = threadIdx.x;
    #pragma unroll
    for (int i = 0; i < 4; ++i) {
        int idx = (i * 1024 + t) * 4;
        float4 sv = *(const float4*)(s_acc + idx);
        float4 dv = *(const float4*)(diag + idx);
        acc += __builtin_amdgcn_logf(sv.x) * LN2 + INV_T - dv.x;
        acc += __builtin_amdgcn_logf(sv.y) * LN2 + INV_T - dv.y;
        acc += __builtin_amdgcn_logf(sv.z) * LN2 + INV_T - dv.z;
        acc += __builtin_amdgcn_logf(sv.w) * LN2 + INV_T - dv.w;
    }
    #pragma unroll
    for (int m = 1; m < 64; m <<= 1) acc += __shfl_xor(acc, m);
    __shared__ float wsum[16];
    if ((t & 63) == 0) wsum[t >> 6] = acc;
    __syncthreads();
    if (t == 0) {
        float r = 0.f;
        #pragma unroll
        for (int i = 0; i < 16; ++i) r += wsum[i];
        out[0] = r / (float)N_ROWS;
    }
}

// ---------------------------------------------------------------------------
extern "C" void kernel_launch(void* const* d_in, const int* in_sizes, int n_in,
                              void* d_out, int out_size, void* d_ws, size_t ws_size,
                              hipStream_t stream)
{
    const float* A = (const float*)d_in[0];
    const float* P = (const float*)d_in[1];
    float* out = (float*)d_out;

    char* ws = (char*)d_ws;
    ushort* a16  = (ushort*)ws;                                   // 4 MB
    ushort* p16t = (ushort*)(ws + (size_t)4 * 1024 * 1024);       // 4 MB tiled
    float*  diag = (float*)(ws + (size_t)8 * 1024 * 1024);        // 64 KB
    float*  sacc = (float*)(ws + (size_t)8 * 1024 * 1024 + 65536);

    hipMemsetAsync(sacc, 0, N_ROWS * sizeof(float), stream);
    norm_kernel<<<N_ROWS / 4, 256, 0, stream>>>(A, P, a16, p16t, diag);
    lse_kernel<<<(N_ROWS / BM) * COLSPLIT, 256, 0, stream>>>(a16, p16t, sacc);
    finalize_kernel<<<1, 1024, 0, stream>>>(sacc, diag, out);
}

// Round 11
// 96.009 us; speedup vs baseline: 1.4132x; 1.0477x over previous
//
#include <hip/hip_runtime.h>
#include <hip/hip_bf16.h>

#define N_ROWS 16384
#define DIM 128

constexpr float INV_T = 1.0f / 0.07f;                 // 14.2857...
constexpr float LOG2E = 1.4426950408889634f;
constexpr float C1    = INV_T * LOG2E;                // exp2 scale, folded into A
constexpr float LN2   = 0.69314718055994530942f;

typedef short bf16x8 __attribute__((ext_vector_type(8)));
typedef float f32x16 __attribute__((ext_vector_type(16)));

typedef const __attribute__((address_space(1))) void* gptr1_t;
typedef __attribute__((address_space(3))) void*       sptr3_t;

__device__ __forceinline__ ushort f2bf(float x) {
    unsigned u = __float_as_uint(x);
    u += 0x7fffu + ((u >> 16) & 1u);                  // RTNE
    return (ushort)(u >> 16);
}

// p stored PRE-TILED in B-fragment order, 32-col tiles of 8KB:
//   layout [tile32][kf8][hi2][c31 32]x(8 bf16)
//   col j: tile=j>>5, c31=j&31 ; k: kf=k>>4, hi=(k>>3)&1, e=k&7
#define TILE_U16 4096                 /* 32 cols x 128 k = 8 KB           */
#define TILE_BYTES 8192
#define BM 256                        /* rows per block (4 waves x 64)    */
#define WROWS 64
#define COLSPLIT 16
#define COLS_PER (N_ROWS / COLSPLIT)  /* 1024 */
#define NJT (COLS_PER / 32)           /* 32 tiles */

// ---------------------------------------------------------------------------
// Kernel 1: normalize; A scaled by C1 (exp2 fold); P written tiled (32-col);
// exact fp32 diagonal logit.
// ---------------------------------------------------------------------------
__global__ __launch_bounds__(256) void norm_kernel(
    const float* __restrict__ A, const float* __restrict__ P,
    ushort* __restrict__ a16, ushort* __restrict__ p16t,
    float* __restrict__ diag)
{
    int row  = blockIdx.x * 4 + (threadIdx.x >> 6);
    int lane = threadIdx.x & 63;
    float2 av = *(const float2*)(A + (size_t)row * DIM + lane * 2);
    float2 pv = *(const float2*)(P + (size_t)row * DIM + lane * 2);
    float ssa = av.x * av.x + av.y * av.y;
    float ssp = pv.x * pv.x + pv.y * pv.y;
    float dp  = av.x * pv.x + av.y * pv.y;
    #pragma unroll
    for (int m = 1; m < 64; m <<= 1) {
        ssa += __shfl_xor(ssa, m);
        ssp += __shfl_xor(ssp, m);
        dp  += __shfl_xor(dp,  m);
    }
    float ra = 1.0f / fmaxf(sqrtf(ssa), 1e-12f);
    float rp = 1.0f / fmaxf(sqrtf(ssp), 1e-12f);
    if (lane == 0) diag[row] = dp * ra * rp * INV_T;
    float sa = ra * C1;
    ushort2 a2, p2;
    a2.x = f2bf(av.x * sa); a2.y = f2bf(av.y * sa);
    p2.x = f2bf(pv.x * rp); p2.y = f2bf(pv.y * rp);
    *(ushort2*)(a16 + (size_t)row * DIM + lane * 2) = a2;
    // k = 2*lane: kf=lane>>3, hi=(lane>>2)&1, e=2*(lane&3)  (verified R10 map)
    size_t off = (size_t)(row >> 5) * TILE_U16 + (lane >> 3) * 512
               + ((lane >> 2) & 1) * 256 + (row & 31) * 8 + (lane & 3) * 2;
    *(ushort2*)(p16t + off) = p2;
}

// ---------------------------------------------------------------------------
// Kernel 2: per-row sum of exp2(C1*cos - C1) via 32x32x16 bf16 MFMA.
// T3/T4 schedule: raw s_barrier + COUNTED vmcnt (never 0 in main loop),
// triple-buffered 8KB tiles, staging 2 tiles ahead via global_load_lds.
// Race audit: round j reads buf[j%3]; stage of tile j+2 -> buf[(j+2)%3]
// is issued AFTER barrier j, and that buffer's last readers (round j-1)
// arrived at barrier j only after completing their reads.  vmcnt(2) before
// barrier j bounds the oldest outstanding stage (tile j) per wave.
// REG-CAP DISCIPLINE: (256,2) ONLY — tighter caps spill (R2/R4/R6).
// ---------------------------------------------------------------------------
__global__ __launch_bounds__(256, 2) void lse_kernel(
    const ushort* __restrict__ a16, const ushort* __restrict__ p16t,
    float* __restrict__ s_accum)
{
    __shared__ __attribute__((aligned(16))) ushort btile[3][TILE_U16];

    int colseg = blockIdx.x & (COLSPLIT - 1);   // round-robin -> XCD-pinned
    int rowblk = blockIdx.x / COLSPLIT;
    int wave = threadIdx.x >> 6;
    int lane = threadIdx.x & 63;
    int c31  = lane & 31, hi = lane >> 5;
    int row0 = rowblk * BM + wave * WROWS;

    // A fragments: 2 row-tiles x 8 K-frags (K=16 each), 8 bf16/lane.
    bf16x8 afrag[2][8];
    #pragma unroll
    for (int t = 0; t < 2; ++t)
        #pragma unroll
        for (int kf = 0; kf < 8; ++kf)
            afrag[t][kf] = *(const bf16x8*)(
                a16 + (size_t)(row0 + t * 32 + c31) * DIM + kf * 16 + hi * 8);

    f32x16 cinit;
    #pragma unroll
    for (int r = 0; r < 16; ++r) cinit[r] = -C1;

    float s0[16], s1[16];
    #pragma unroll
    for (int r = 0; r < 16; ++r) { s0[r] = 0.f; s1[r] = 0.f; }

    const char* seg = (const char*)p16t + (size_t)colseg * NJT * TILE_BYTES;
    char* lds = (char*)&btile[0][0];
    // this wave stages chunks {2*wave, 2*wave+1} of each 8-chunk tile
    int choff = wave * 2048 + lane * 16;

    // prologue: stage tiles 0 and 1 (2 loads each; 4 outstanding)
    __builtin_amdgcn_global_load_lds((gptr1_t)(seg + choff),
                                     (sptr3_t)(lds + choff), 16, 0, 0);
    __builtin_amdgcn_global_load_lds((gptr1_t)(seg + choff + 1024),
                                     (sptr3_t)(lds + choff + 1024), 16, 0, 0);
    __builtin_amdgcn_global_load_lds((gptr1_t)(seg + TILE_BYTES + choff),
                                     (sptr3_t)(lds + TILE_BYTES + choff), 16, 0, 0);
    __builtin_amdgcn_global_load_lds((gptr1_t)(seg + TILE_BYTES + choff + 1024),
                                     (sptr3_t)(lds + TILE_BYTES + choff + 1024), 16, 0, 0);

    int cur = 0;
    for (int jt = 0; jt < NJT; ++jt) {
        // counted wait: oldest 2 outstanding loads = stage of tile jt
        if (jt < NJT - 1) asm volatile("s_waitcnt vmcnt(2)" ::: "memory");
        else              asm volatile("s_waitcnt vmcnt(0)" ::: "memory");
        __builtin_amdgcn_s_barrier();
        __builtin_amdgcn_sched_barrier(0);

        if (jt + 2 < NJT) {            // stage tile jt+2 (2 loads, no wait)
            int stg = cur + 2; if (stg >= 3) stg -= 3;
            const char* src = seg + (size_t)(jt + 2) * TILE_BYTES + choff;
            char* dst = lds + stg * TILE_BYTES + choff;
            __builtin_amdgcn_global_load_lds((gptr1_t)src,
                                             (sptr3_t)dst, 16, 0, 0);
            __builtin_amdgcn_global_load_lds((gptr1_t)(src + 1024),
                                             (sptr3_t)(dst + 1024), 16, 0, 0);
        }

        const ushort* tb = (const ushort*)(lds + cur * TILE_BYTES) + lane * 8;
        bf16x8 b0 = *(const bf16x8*)(tb);
        __builtin_amdgcn_s_setprio(1);
        f32x16 acc0 = __builtin_amdgcn_mfma_f32_32x32x16_bf16(
            afrag[0][0], b0, cinit, 0, 0, 0);
        f32x16 acc1 = __builtin_amdgcn_mfma_f32_32x32x16_bf16(
            afrag[1][0], b0, cinit, 0, 0, 0);
        #pragma unroll
        for (int kf = 1; kf < 8; ++kf) {
            bf16x8 b = *(const bf16x8*)(tb + kf * 512);
            acc0 = __builtin_amdgcn_mfma_f32_32x32x16_bf16(
                afrag[0][kf], b, acc0, 0, 0, 0);
            acc1 = __builtin_amdgcn_mfma_f32_32x32x16_bf16(
                afrag[1][kf], b, acc1, 0, 0, 0);
        }
        __builtin_amdgcn_s_setprio(0);
        #pragma unroll
        for (int r = 0; r < 16; ++r) {
            s0[r] += __builtin_amdgcn_exp2f(acc0[r]);
            s1[r] += __builtin_amdgcn_exp2f(acc1[r]);
        }
        cur = (cur == 2) ? 0 : cur + 1;
    }

    // reduce each row's 32 column-lanes (within each 32-lane half), one atomic
    #pragma unroll
    for (int t = 0; t < 2; ++t)
        #pragma unroll
        for (int r = 0; r < 16; ++r) {
            float v = (t ? s1[r] : s0[r]);
            v += __shfl_xor(v, 1);
            v += __shfl_xor(v, 2);
            v += __shfl_xor(v, 4);
            v += __shfl_xor(v, 8);
            v += __shfl_xor(v, 16);
            if (c31 == 0)
                atomicAdd(&s_accum[row0 + t * 32 + (r & 3) + 8 * (r >> 2) + 4 * hi], v);
        }
}

// ---------------------------------------------------------------------------
// Kernel 3: loss = mean( ln(s_i) + 1/T - diag_i )
// ---------------------------------------------------------------------------
__global__ __launch_bounds__(1024) void finalize_kernel(
    const float* __restrict__ s_acc, const float* __restrict__ diag,
    float* __restrict__ out)
{
    float acc = 0.f;
    int t = threadIdx.x;
    #pragma unroll
    for (int i = 0; i < 4; ++i) {
        int idx = (i * 1024 + t) * 4;
        float4 sv = *(const float4*)(s_acc + idx);
        float4 dv = *(const float4*)(diag + idx);
        acc += __builtin_amdgcn_logf(sv.x) * LN2 + INV_T - dv.x;
        acc += __builtin_amdgcn_logf(sv.y) * LN2 + INV_T - dv.y;
        acc += __builtin_amdgcn_logf(sv.z) * LN2 + INV_T - dv.z;
        acc += __builtin_amdgcn_logf(sv.w) * LN2 + INV_T - dv.w;
    }
    #pragma unroll
    for (int m = 1; m < 64; m <<= 1) acc += __shfl_xor(acc, m);
    __shared__ float wsum[16];
    if ((t & 63) == 0) wsum[t >> 6] = acc;
    __syncthreads();
    if (t == 0) {
        float r = 0.f;
        #pragma unroll
        for (int i = 0; i < 16; ++i) r += wsum[i];
        out[0] = r / (float)N_ROWS;
    }
}

// ---------------------------------------------------------------------------
extern "C" void kernel_launch(void* const* d_in, const int* in_sizes, int n_in,
                              void* d_out, int out_size, void* d_ws, size_t ws_size,
                              hipStream_t stream)
{
    const float* A = (const float*)d_in[0];
    const float* P = (const float*)d_in[1];
    float* out = (float*)d_out;

    char* ws = (char*)d_ws;
    ushort* a16  = (ushort*)ws;                                   // 4 MB
    ushort* p16t = (ushort*)(ws + (size_t)4 * 1024 * 1024);       // 4 MB tiled
    float*  diag = (float*)(ws + (size_t)8 * 1024 * 1024);        // 64 KB
    float*  sacc = (float*)(ws + (size_t)8 * 1024 * 1024 + 65536);

    hipMemsetAsync(sacc, 0, N_ROWS * sizeof(float), stream);
    norm_kernel<<<N_ROWS / 4, 256, 0, stream>>>(A, P, a16, p16t, diag);
    lse_kernel<<<(N_ROWS / BM) * COLSPLIT, 256, 0, stream>>>(a16, p16t, sacc);
    finalize_kernel<<<1, 1024, 0, stream>>>(sacc, diag, out);
}